// Round 8
// baseline (791.773 us; speedup 1.0000x reference)
//
#include <hip/hip_runtime.h>
#include <hip/hip_bf16.h>
#include <hip/hip_fp16.h>

typedef __hip_bfloat16 bf16;
typedef __attribute__((ext_vector_type(8))) short short8;   // 8 bf16 raw (4 VGPRs)
typedef __attribute__((ext_vector_type(4))) float f32x4;
typedef __attribute__((ext_vector_type(2))) _Float16 h16x2; // packed f16 pair

#if defined(__has_builtin)
#if __has_builtin(__builtin_amdgcn_fdot2)
#define HAVE_FDOT2 1
#endif
#endif

__device__ __forceinline__ float braw2f(unsigned short u) {
    return __uint_as_float(((unsigned int)u) << 16);
}
__device__ __forceinline__ unsigned short f2braw(float f) {
    bf16 b = __float2bfloat16(f);
    return *(unsigned short*)&b;
}
__device__ __forceinline__ unsigned int pack2(float lo, float hi) {
    return (unsigned int)f2braw(lo) | ((unsigned int)f2braw(hi) << 16);
}
// pack two floats as f16 pair (payload format for the fdot2 segment kernel)
__device__ __forceinline__ unsigned int pack2h(float lo, float hi) {
    __half l = __float2half(lo), h = __float2half(hi);
    return (unsigned int)*(unsigned short*)&l | ((unsigned int)*(unsigned short*)&h << 16);
}
// v_dot2_f32_f16: c += a.x*b.x + a.y*b.y in ONE VALU op (f32 accumulate)
__device__ __forceinline__ float fdot2(h16x2 a, h16x2 b, float c) {
#ifdef HAVE_FDOT2
    return __builtin_amdgcn_fdot2(a, b, c, false);
#else
    return c + (float)a[0] * (float)b[0] + (float)a[1] * (float)b[1];
#endif
}
__device__ __forceinline__ h16x2 u2h2(unsigned int u) {
    union { unsigned int u; h16x2 h; } cv; cv.u = u; return cv.h;
}

#define LN2F 0.69314718055994531f
// shifted softplus via native HW transcendentals (v_exp/v_log). Stable: arg<=0.
__device__ __forceinline__ float ssp(float x) {
    return fmaxf(x, 0.0f) + __logf(1.0f + __expf(-fabsf(x))) - LN2F;
}

// MFMA linear (round-8, verified): Y = (ACT? ssp:id)(X @ W^T + B), K=N=128.
// Block = 64 rows; in-place safe (block-private rows + barrier).
template<bool ACT, bool OUT_BF16>
__global__ __launch_bounds__(256) void linear128_mfma_kernel(
    const float* __restrict__ X, const float* __restrict__ W, const float* __restrict__ Bias,
    void* __restrict__ Yv, int n_rows)
{
    __shared__ unsigned short wls[128 * 128];
    __shared__ unsigned short xs[64 * 128];
    __shared__ float bls[128];

    const float4* W4 = (const float4*)W;
    for (int i = threadIdx.x; i < 128 * 32; i += 256) {
        float4 w = W4[i];
        ushort4 s; s.x = f2braw(w.x); s.y = f2braw(w.y); s.z = f2braw(w.z); s.w = f2braw(w.w);
        *(ushort4*)&wls[i * 4] = s;
    }
    if (threadIdx.x < 128) bls[threadIdx.x] = Bias[threadIdx.x];

    const int base = blockIdx.x * 64;
    const float4* X4 = (const float4*)X;
    for (int i = threadIdx.x; i < 64 * 32; i += 256) {
        int r = i >> 5, k4 = i & 31;
        int row = base + r;
        float4 v = (row < n_rows) ? X4[(size_t)row * 32 + k4] : make_float4(0.f, 0.f, 0.f, 0.f);
        ushort4 s; s.x = f2braw(v.x); s.y = f2braw(v.y); s.z = f2braw(v.z); s.w = f2braw(v.w);
        *(ushort4*)&xs[r * 128 + k4 * 4] = s;
    }
    __syncthreads();

    const int wv = threadIdx.x >> 6;
    const int l  = threadIdx.x & 63;
    const int lm = l & 15;
    const int lq = l >> 4;

    short8 a[4];
    #pragma unroll
    for (int kk = 0; kk < 4; ++kk)
        a[kk] = *(const short8*)&xs[(wv * 16 + lm) * 128 + kk * 32 + lq * 8];

    f32x4 acc[8];
    #pragma unroll
    for (int ct = 0; ct < 8; ++ct) {
        f32x4 c = {0.f, 0.f, 0.f, 0.f};
        #pragma unroll
        for (int kk = 0; kk < 4; ++kk) {
            short8 b = *(const short8*)&wls[(ct * 16 + lm) * 128 + kk * 32 + lq * 8];
            c = __builtin_amdgcn_mfma_f32_16x16x32_bf16(a[kk], b, c, 0, 0, 0);
        }
        acc[ct] = c;
    }

    #pragma unroll
    for (int ct = 0; ct < 8; ++ct) {
        int col = ct * 16 + lm;
        float bia = bls[col];
        #pragma unroll
        for (int r = 0; r < 4; ++r) {
            int row = base + wv * 16 + lq * 4 + r;
            if (row < n_rows) {
                float o = acc[ct][r] + bia;
                if (ACT) o = ssp(o);
                if (OUT_BF16) ((unsigned short*)Yv)[(size_t)row * 128 + col] = f2braw(o);
                else          ((float*)Yv)[(size_t)row * 128 + col] = o;
            }
        }
    }
}

// ---- counting sort by idx_i ----

__global__ __launch_bounds__(256) void zero_int_kernel(int* __restrict__ p, int n) {
    int i = blockIdx.x * 256 + threadIdx.x;
    if (i < n) p[i] = 0;
}

__global__ __launch_bounds__(256) void hist_kernel(
    const int* __restrict__ idx_i, int* __restrict__ cnt, int n_pairs, int n_atoms)
{
    for (int p = blockIdx.x * 256 + threadIdx.x; p < n_pairs; p += gridDim.x * 256) {
        int ai = idx_i[p];
        if ((unsigned)ai < (unsigned)n_atoms) atomicAdd(&cnt[ai], 1);
    }
}

__global__ __launch_bounds__(1024) void scan1_kernel(
    const int* __restrict__ cnt, int* __restrict__ offs, int* __restrict__ partials, int n)
{
    __shared__ int sm[1024];
    int t = threadIdx.x, idx = blockIdx.x * 1024 + t;
    int v = (idx < n) ? cnt[idx] : 0;
    sm[t] = v;
    __syncthreads();
    #pragma unroll
    for (int d = 1; d < 1024; d <<= 1) {
        int tmp = (t >= d) ? sm[t - d] : 0;
        __syncthreads();
        sm[t] += tmp;
        __syncthreads();
    }
    if (idx < n) offs[idx] = sm[t] - v;
    if (t == 1023) partials[blockIdx.x] = sm[1023];
}

__global__ __launch_bounds__(64) void scan2_kernel(
    int* __restrict__ partials, int* __restrict__ offs, int nb, int n)
{
    __shared__ int sm[64];
    int t = threadIdx.x;
    int v = (t < nb) ? partials[t] : 0;
    sm[t] = v;
    __syncthreads();
    #pragma unroll
    for (int d = 1; d < 64; d <<= 1) {
        int tmp = (t >= d) ? sm[t - d] : 0;
        __syncthreads();
        sm[t] += tmp;
        __syncthreads();
    }
    if (t < nb) partials[t] = sm[t] - v;
    if (t == 63) offs[n] = sm[63];
}

__global__ __launch_bounds__(1024) void scan3_kernel(
    int* __restrict__ offs, int* __restrict__ cur, const int* __restrict__ partials, int n)
{
    int idx = blockIdx.x * 1024 + threadIdx.x;
    if (idx < n) {
        int o = offs[idx] + partials[blockIdx.x];
        offs[idx] = o;
        cur[idx] = o;
    }
}

// ---------- PAYLOAD PATH: physically sort pair payload ----------
// payload[pos] = { f_ij F16 x20 (40 B) | idx_j int (4 B) | rcut f32 (4 B) } = 48 B
// (f16, not bf16: feeds v_dot2_f32_f16 in the segment kernel with no unpacking;
// f16 also has 2 more mantissa bits than bf16 for f_ij in [0,1).)
// Block 0 additionally zeroes an 816 B slack region after the payload.
__global__ __launch_bounds__(256) void scatter_pay_kernel(
    const float* __restrict__ f_ij, const int* __restrict__ idx_i, const int* __restrict__ idx_j,
    const float* __restrict__ rcut, int* __restrict__ cur, uint4* __restrict__ pay,
    int n_pairs, int n_atoms)
{
    if (blockIdx.x == 0 && threadIdx.x < 204) {
        ((int*)(pay + (size_t)n_pairs * 3))[threadIdx.x] = 0;
    }
    for (int p = blockIdx.x * 256 + threadIdx.x; p < n_pairs; p += gridDim.x * 256) {
        int ai = idx_i[p];
        if ((unsigned)ai >= (unsigned)n_atoms) continue;
        int pos = atomicAdd(&cur[ai], 1);
        const float4* fr = (const float4*)(f_ij + (size_t)p * 20);
        float4 f0 = fr[0], f1 = fr[1], f2 = fr[2], f3 = fr[3], f4 = fr[4];
        uint4 q0, q1, q2;
        q0.x = pack2h(f0.x, f0.y); q0.y = pack2h(f0.z, f0.w);
        q0.z = pack2h(f1.x, f1.y); q0.w = pack2h(f1.z, f1.w);
        q1.x = pack2h(f2.x, f2.y); q1.y = pack2h(f2.z, f2.w);
        q1.z = pack2h(f3.x, f3.y); q1.w = pack2h(f3.z, f3.w);
        q2.x = pack2h(f4.x, f4.y); q2.y = pack2h(f4.z, f4.w);
        q2.z = (unsigned int)idx_j[p];
        q2.w = __float_as_uint(rcut[p]);
        uint4* dst = pay + (size_t)pos * 3;
        dst[0] = q0; dst[1] = q1; dst[2] = q2;
    }
}

// ---------- TIER-1: segment over sorted f16 payload, fdot2 + persistent waves ----------
// v2 (round 8): persistent waves with dynamic atom assignment. Round-7 counters
// showed OccupancyPercent 64% with VGPR=32/LDS=0 — a time-averaged wave-drain:
// a 4-wave block retires on its LONGEST of 4 segments (max of 4 Poisson(16) draws
// ~ 21 vs mean 16, ~30% idle slots). Fix: each wave pulls atom indices from a
// global atomicAdd counter (lane 0 + shfl broadcast); no wave idles until global
// work runs out, and resident waves stay at cap -> deeper latency hiding for the
// payload->idx_j->h-gather chain. W_f register setup also amortizes over ~5
// atoms/wave. Inner loop identical to the verified round-7 kernel.
__global__ __launch_bounds__(256) void segment_pay_f16_kernel(
    const uint4* __restrict__ pay, const float* __restrict__ W_f,
    const float* __restrict__ b_f, const unsigned int* __restrict__ hb32,
    const int* __restrict__ offs, int* __restrict__ work_ctr,
    float* __restrict__ agg, int n_atoms)
{
    const int lane = threadIdx.x & 63;

    const int c0 = 2 * lane;
    // packed W_f: w0p[r] = (W_f[c0][2r], W_f[c0][2r+1]) as f16 pair; w1p for c0+1
    h16x2 w0p[10], w1p[10];
    #pragma unroll
    for (int r = 0; r < 10; ++r) {
        h16x2 a, b;
        a[0] = (_Float16)W_f[c0 * 20 + 2 * r];
        a[1] = (_Float16)W_f[c0 * 20 + 2 * r + 1];
        b[0] = (_Float16)W_f[(c0 + 1) * 20 + 2 * r];
        b[1] = (_Float16)W_f[(c0 + 1) * 20 + 2 * r + 1];
        w0p[r] = a; w1p[r] = b;
    }
    const float b0 = b_f[c0], b1 = b_f[c0 + 1];

    for (;;) {
        int wave_atom = 0;
        if (lane == 0) wave_atom = atomicAdd(work_ctr, 1);
        wave_atom = __shfl(wave_atom, 0);
        if (wave_atom >= n_atoms) break;

        const int cs = offs[wave_atom], ce = offs[wave_atom + 1];
        float acc0 = 0.f, acc1 = 0.f;

        int s = cs;
        for (; s + 2 <= ce; s += 2) {
            const uint4* pA = pay + (size_t)s * 3;
            const uint4* pB = pA + 3;
            uint4 qA0 = pA[0], qA1 = pA[1], qA2 = pA[2];
            uint4 qB0 = pB[0], qB1 = pB[1], qB2 = pB[2];
            unsigned int uA[10] = {qA0.x,qA0.y,qA0.z,qA0.w,qA1.x,qA1.y,qA1.z,qA1.w,qA2.x,qA2.y};
            unsigned int uB[10] = {qB0.x,qB0.y,qB0.z,qB0.w,qB1.x,qB1.y,qB1.z,qB1.w,qB2.x,qB2.y};
            float a0A = b0, a1A = b1, a0B = b0, a1B = b1;
            #pragma unroll
            for (int r = 0; r < 10; ++r) {
                h16x2 fA = u2h2(uA[r]);
                h16x2 fB = u2h2(uB[r]);
                a0A = fdot2(fA, w0p[r], a0A);
                a1A = fdot2(fA, w1p[r], a1A);
                a0B = fdot2(fB, w0p[r], a0B);
                a1B = fdot2(fB, w1p[r], a1B);
            }
            float rcA = __uint_as_float(qA2.w), rcB = __uint_as_float(qB2.w);
            float wv0A = ssp(a0A) * rcA, wv1A = ssp(a1A) * rcA;
            float wv0B = ssp(a0B) * rcB, wv1B = ssp(a1B) * rcB;
            unsigned int hA = hb32[(size_t)(int)qA2.z * 64 + lane];
            unsigned int hB = hb32[(size_t)(int)qB2.z * 64 + lane];
            acc0 += __uint_as_float(hA << 16) * wv0A + __uint_as_float(hB << 16) * wv0B;
            acc1 += __uint_as_float(hA & 0xffff0000u) * wv1A + __uint_as_float(hB & 0xffff0000u) * wv1B;
        }
        if (s < ce) {
            const uint4* pA = pay + (size_t)s * 3;
            uint4 q0 = pA[0], q1 = pA[1], q2 = pA[2];
            unsigned int u[10] = {q0.x,q0.y,q0.z,q0.w,q1.x,q1.y,q1.z,q1.w,q2.x,q2.y};
            float a0 = b0, a1 = b1;
            #pragma unroll
            for (int r = 0; r < 10; ++r) {
                h16x2 f = u2h2(u[r]);
                a0 = fdot2(f, w0p[r], a0);
                a1 = fdot2(f, w1p[r], a1);
            }
            float rc = __uint_as_float(q2.w);
            float wv0 = ssp(a0) * rc, wv1 = ssp(a1) * rc;
            unsigned int h = hb32[(size_t)(int)q2.z * 64 + lane];
            acc0 += __uint_as_float(h << 16) * wv0;
            acc1 += __uint_as_float(h & 0xffff0000u) * wv1;
        }

        *(float2*)&agg[(size_t)wave_atom * 128 + c0] = make_float2(acc0, acc1);
    }
}

// ---------- TIER-2 FALLBACK (proven): perm-indirected segment ----------
__global__ __launch_bounds__(256) void scatter_kernel(
    const int* __restrict__ idx_i, int* __restrict__ cur, int* __restrict__ perm,
    int n_pairs, int n_atoms)
{
    for (int p = blockIdx.x * 256 + threadIdx.x; p < n_pairs; p += gridDim.x * 256) {
        int ai = idx_i[p];
        if ((unsigned)ai < (unsigned)n_atoms) {
            int pos = atomicAdd(&cur[ai], 1);
            perm[pos] = p;
        }
    }
}

__global__ __launch_bounds__(256) void segment_kernel(
    const float* __restrict__ f_ij, const int* __restrict__ idx_j,
    const float* __restrict__ rcut, const float* __restrict__ W_f,
    const float* __restrict__ b_f, const unsigned short* __restrict__ hb,
    const int* __restrict__ offs, const int* __restrict__ perm,
    float* __restrict__ agg, int n_atoms)
{
    const int wave = (blockIdx.x * 256 + threadIdx.x) >> 6;
    const int lane = threadIdx.x & 63;
    if (wave >= n_atoms) return;

    float w0[20], w1[20];
    #pragma unroll
    for (int r = 0; r < 20; ++r) {
        w0[r] = W_f[lane * 20 + r];
        w1[r] = W_f[(lane + 64) * 20 + r];
    }
    const float b0 = b_f[lane], b1 = b_f[lane + 64];

    const int cs = offs[wave], ce = offs[wave + 1];
    float acc0 = 0.f, acc1 = 0.f;

    int s = cs;
    for (; s + 2 <= ce; s += 2) {
        int pA = perm[s], pB = perm[s + 1];
        int ajA = idx_j[pA], ajB = idx_j[pB];
        float rcA = rcut[pA], rcB = rcut[pB];
        const float4* frA = (const float4*)(f_ij + (size_t)pA * 20);
        const float4* frB = (const float4*)(f_ij + (size_t)pB * 20);
        float a0A = b0, a1A = b1, a0B = b0, a1B = b1;
        #pragma unroll
        for (int q = 0; q < 5; ++q) {
            float4 fA = frA[q], fB = frB[q];
            a0A += fA.x * w0[4*q+0]; a1A += fA.x * w1[4*q+0];
            a0A += fA.y * w0[4*q+1]; a1A += fA.y * w1[4*q+1];
            a0A += fA.z * w0[4*q+2]; a1A += fA.z * w1[4*q+2];
            a0A += fA.w * w0[4*q+3]; a1A += fA.w * w1[4*q+3];
            a0B += fB.x * w0[4*q+0]; a1B += fB.x * w1[4*q+0];
            a0B += fB.y * w0[4*q+1]; a1B += fB.y * w1[4*q+1];
            a0B += fB.z * w0[4*q+2]; a1B += fB.z * w1[4*q+2];
            a0B += fB.w * w0[4*q+3]; a1B += fB.w * w1[4*q+3];
        }
        float wv0A = ssp(a0A) * rcA, wv1A = ssp(a1A) * rcA;
        float wv0B = ssp(a0B) * rcB, wv1B = ssp(a1B) * rcB;
        float h0A = braw2f(hb[(size_t)ajA * 128 + lane]);
        float h1A = braw2f(hb[(size_t)ajA * 128 + 64 + lane]);
        float h0B = braw2f(hb[(size_t)ajB * 128 + lane]);
        float h1B = braw2f(hb[(size_t)ajB * 128 + 64 + lane]);
        acc0 += h0A * wv0A + h0B * wv0B;
        acc1 += h1A * wv1A + h1B * wv1B;
    }
    if (s < ce) {
        int p = perm[s];
        int aj = idx_j[p];
        float rc = rcut[p];
        const float4* fr = (const float4*)(f_ij + (size_t)p * 20);
        float a0 = b0, a1 = b1;
        #pragma unroll
        for (int q = 0; q < 5; ++q) {
            float4 fv = fr[q];
            a0 += fv.x * w0[4*q+0]; a1 += fv.x * w1[4*q+0];
            a0 += fv.y * w0[4*q+1]; a1 += fv.y * w1[4*q+1];
            a0 += fv.z * w0[4*q+2]; a1 += fv.z * w1[4*q+2];
            a0 += fv.w * w0[4*q+3]; a1 += fv.w * w1[4*q+3];
        }
        float wv0 = ssp(a0) * rc, wv1 = ssp(a1) * rc;
        acc0 += braw2f(hb[(size_t)aj * 128 + lane]) * wv0;
        acc1 += braw2f(hb[(size_t)aj * 128 + 64 + lane]) * wv1;
    }

    agg[(size_t)wave * 128 + lane]      = acc0;
    agg[(size_t)wave * 128 + 64 + lane] = acc1;
}

static inline size_t align_up(size_t v, size_t a) { return (v + a - 1) & ~(a - 1); }

extern "C" void kernel_launch(void* const* d_in, const int* in_sizes, int n_in,
                              void* d_out, int out_size, void* d_ws, size_t ws_size,
                              hipStream_t stream) {
    const float* x     = (const float*)d_in[0];
    const float* f_ij  = (const float*)d_in[1];
    const int*   idx_i = (const int*)d_in[2];
    const int*   idx_j = (const int*)d_in[3];
    const float* rcut  = (const float*)d_in[4];
    const float* W_in  = (const float*)d_in[5];
    const float* b_in  = (const float*)d_in[6];
    const float* W_f   = (const float*)d_in[7];
    const float* b_f   = (const float*)d_in[8];
    const float* W_out = (const float*)d_in[9];
    const float* b_out = (const float*)d_in[10];

    const int n_atoms = in_sizes[0] / 128;   // 40000
    const int n_pairs = in_sizes[2];         // 640000
    const int nscan = (n_atoms + 1023) / 1024;
    const int mfma_grid = (n_atoms + 63) / 64;

    // Tier-1 ws layout (payload path). cur gets ONE extra int: the persistent-wave
    // work counter (zeroed with cur; untouched by hist/scan/scatter which only
    // write indices < n_atoms).
    size_t off_hb   = 0;
    size_t off_offs = align_up(off_hb + (size_t)n_atoms * 128 * 2, 16);
    size_t off_cur  = align_up(off_offs + (size_t)(n_atoms + 1) * 4, 16);
    size_t off_part = align_up(off_cur + (size_t)(n_atoms + 1) * 4, 16);
    size_t off_pay  = align_up(off_part + (size_t)nscan * 4, 64);
    size_t need_pay = off_pay + (size_t)n_pairs * 48 + 816;

    if (ws_size >= need_pay) {
        // ---------- tier-1: f16 payload + fdot2 + persistent-wave segment ----------
        unsigned short* hb = (unsigned short*)((char*)d_ws + off_hb);
        int*  offs = (int*)((char*)d_ws + off_offs);
        int*  cur  = (int*)((char*)d_ws + off_cur);
        int*  part = (int*)((char*)d_ws + off_part);
        uint4* pay = (uint4*)((char*)d_ws + off_pay);
        int*  work_ctr = cur + n_atoms;      // extra cell after cur
        float* agg = (float*)d_out;

        linear128_mfma_kernel<false, true><<<dim3(mfma_grid), dim3(256), 0, stream>>>(
            x, W_in, b_in, (void*)hb, n_atoms);

        zero_int_kernel<<<dim3((n_atoms + 1 + 255) / 256), dim3(256), 0, stream>>>(
            cur, n_atoms + 1);
        hist_kernel<<<dim3(1024), dim3(256), 0, stream>>>(idx_i, cur, n_pairs, n_atoms);
        scan1_kernel<<<dim3(nscan), dim3(1024), 0, stream>>>(cur, offs, part, n_atoms);
        scan2_kernel<<<dim3(1), dim3(64), 0, stream>>>(part, offs, nscan, n_atoms);
        scan3_kernel<<<dim3(nscan), dim3(1024), 0, stream>>>(offs, cur, part, n_atoms);
        scatter_pay_kernel<<<dim3(1024), dim3(256), 0, stream>>>(
            f_ij, idx_i, idx_j, rcut, cur, pay, n_pairs, n_atoms);

        segment_pay_f16_kernel<<<dim3(2048), dim3(256), 0, stream>>>(
            pay, W_f, b_f, (const unsigned int*)hb, offs, work_ctr, agg, n_atoms);

        linear128_mfma_kernel<true, false><<<dim3(mfma_grid), dim3(256), 0, stream>>>(
            agg, W_out, b_out, d_out, n_atoms);
    } else {
        // ---------- tier-2: exact round-8 pipeline (proven 419 µs) ----------
        size_t o_h    = 0;
        size_t o_offs = o_h + (size_t)n_atoms * 128 * 2;
        size_t o_cur  = o_offs + (size_t)(n_atoms + 1) * 4;
        size_t o_perm = o_cur + (size_t)n_atoms * 4;
        size_t o_part = o_perm + (size_t)n_pairs * 4;
        unsigned short* hb = (unsigned short*)((char*)d_ws + o_h);
        int* offs = (int*)((char*)d_ws + o_offs);
        int* cur  = (int*)((char*)d_ws + o_cur);
        int* perm = (int*)((char*)d_ws + o_perm);
        int* part = (int*)((char*)d_ws + o_part);
        float* agg = (float*)d_out;

        linear128_mfma_kernel<false, true><<<dim3(mfma_grid), dim3(256), 0, stream>>>(
            x, W_in, b_in, (void*)hb, n_atoms);

        zero_int_kernel<<<dim3((n_atoms + 255) / 256), dim3(256), 0, stream>>>(cur, n_atoms);
        hist_kernel<<<dim3(1024), dim3(256), 0, stream>>>(idx_i, cur, n_pairs, n_atoms);
        scan1_kernel<<<dim3(nscan), dim3(1024), 0, stream>>>(cur, offs, part, n_atoms);
        scan2_kernel<<<dim3(1), dim3(64), 0, stream>>>(part, offs, nscan, n_atoms);
        scan3_kernel<<<dim3(nscan), dim3(1024), 0, stream>>>(offs, cur, part, n_atoms);
        scatter_kernel<<<dim3(1024), dim3(256), 0, stream>>>(idx_i, cur, perm, n_pairs, n_atoms);

        segment_kernel<<<dim3((n_atoms + 3) / 4), dim3(256), 0, stream>>>(
            f_ij, idx_j, rcut, W_f, b_f, hb, offs, perm, agg, n_atoms);

        linear128_mfma_kernel<true, false><<<dim3(mfma_grid), dim3(256), 0, stream>>>(
            agg, W_out, b_out, d_out, n_atoms);
    }
}

// Round 9
// 338.093 us; speedup vs baseline: 2.3419x; 2.3419x over previous
//
#include <hip/hip_runtime.h>
#include <hip/hip_bf16.h>
#include <hip/hip_fp16.h>

typedef __hip_bfloat16 bf16;
typedef __attribute__((ext_vector_type(8))) short short8;   // 8 bf16 raw (4 VGPRs)
typedef __attribute__((ext_vector_type(4))) float f32x4;
typedef __attribute__((ext_vector_type(2))) _Float16 h16x2; // packed f16 pair

#if defined(__has_builtin)
#if __has_builtin(__builtin_amdgcn_fdot2)
#define HAVE_FDOT2 1
#endif
#endif

__device__ __forceinline__ float braw2f(unsigned short u) {
    return __uint_as_float(((unsigned int)u) << 16);
}
__device__ __forceinline__ unsigned short f2braw(float f) {
    bf16 b = __float2bfloat16(f);
    return *(unsigned short*)&b;
}
__device__ __forceinline__ unsigned int pack2(float lo, float hi) {
    return (unsigned int)f2braw(lo) | ((unsigned int)f2braw(hi) << 16);
}
// pack two floats as f16 pair (payload format for the fdot2 segment kernel)
__device__ __forceinline__ unsigned int pack2h(float lo, float hi) {
    __half l = __float2half(lo), h = __float2half(hi);
    return (unsigned int)*(unsigned short*)&l | ((unsigned int)*(unsigned short*)&h << 16);
}
// v_dot2_f32_f16: c += a.x*b.x + a.y*b.y in ONE VALU op (f32 accumulate)
__device__ __forceinline__ float fdot2(h16x2 a, h16x2 b, float c) {
#ifdef HAVE_FDOT2
    return __builtin_amdgcn_fdot2(a, b, c, false);
#else
    return c + (float)a[0] * (float)b[0] + (float)a[1] * (float)b[1];
#endif
}
__device__ __forceinline__ h16x2 u2h2(unsigned int u) {
    union { unsigned int u; h16x2 h; } cv; cv.u = u; return cv.h;
}

#define LN2F 0.69314718055994531f
// shifted softplus via native HW transcendentals (v_exp/v_log). Stable: arg<=0.
__device__ __forceinline__ float ssp(float x) {
    return fmaxf(x, 0.0f) + __logf(1.0f + __expf(-fabsf(x))) - LN2F;
}

// MFMA linear (round-8, verified): Y = (ACT? ssp:id)(X @ W^T + B), K=N=128.
// Block = 64 rows; in-place safe (block-private rows + barrier).
template<bool ACT, bool OUT_BF16>
__global__ __launch_bounds__(256) void linear128_mfma_kernel(
    const float* __restrict__ X, const float* __restrict__ W, const float* __restrict__ Bias,
    void* __restrict__ Yv, int n_rows)
{
    __shared__ unsigned short wls[128 * 128];
    __shared__ unsigned short xs[64 * 128];
    __shared__ float bls[128];

    const float4* W4 = (const float4*)W;
    for (int i = threadIdx.x; i < 128 * 32; i += 256) {
        float4 w = W4[i];
        ushort4 s; s.x = f2braw(w.x); s.y = f2braw(w.y); s.z = f2braw(w.z); s.w = f2braw(w.w);
        *(ushort4*)&wls[i * 4] = s;
    }
    if (threadIdx.x < 128) bls[threadIdx.x] = Bias[threadIdx.x];

    const int base = blockIdx.x * 64;
    const float4* X4 = (const float4*)X;
    for (int i = threadIdx.x; i < 64 * 32; i += 256) {
        int r = i >> 5, k4 = i & 31;
        int row = base + r;
        float4 v = (row < n_rows) ? X4[(size_t)row * 32 + k4] : make_float4(0.f, 0.f, 0.f, 0.f);
        ushort4 s; s.x = f2braw(v.x); s.y = f2braw(v.y); s.z = f2braw(v.z); s.w = f2braw(v.w);
        *(ushort4*)&xs[r * 128 + k4 * 4] = s;
    }
    __syncthreads();

    const int wv = threadIdx.x >> 6;
    const int l  = threadIdx.x & 63;
    const int lm = l & 15;
    const int lq = l >> 4;

    short8 a[4];
    #pragma unroll
    for (int kk = 0; kk < 4; ++kk)
        a[kk] = *(const short8*)&xs[(wv * 16 + lm) * 128 + kk * 32 + lq * 8];

    f32x4 acc[8];
    #pragma unroll
    for (int ct = 0; ct < 8; ++ct) {
        f32x4 c = {0.f, 0.f, 0.f, 0.f};
        #pragma unroll
        for (int kk = 0; kk < 4; ++kk) {
            short8 b = *(const short8*)&wls[(ct * 16 + lm) * 128 + kk * 32 + lq * 8];
            c = __builtin_amdgcn_mfma_f32_16x16x32_bf16(a[kk], b, c, 0, 0, 0);
        }
        acc[ct] = c;
    }

    #pragma unroll
    for (int ct = 0; ct < 8; ++ct) {
        int col = ct * 16 + lm;
        float bia = bls[col];
        #pragma unroll
        for (int r = 0; r < 4; ++r) {
            int row = base + wv * 16 + lq * 4 + r;
            if (row < n_rows) {
                float o = acc[ct][r] + bia;
                if (ACT) o = ssp(o);
                if (OUT_BF16) ((unsigned short*)Yv)[(size_t)row * 128 + col] = f2braw(o);
                else          ((float*)Yv)[(size_t)row * 128 + col] = o;
            }
        }
    }
}

// ---- counting sort by idx_i ----

__global__ __launch_bounds__(256) void zero_int_kernel(int* __restrict__ p, int n) {
    int i = blockIdx.x * 256 + threadIdx.x;
    if (i < n) p[i] = 0;
}

__global__ __launch_bounds__(256) void hist_kernel(
    const int* __restrict__ idx_i, int* __restrict__ cnt, int n_pairs, int n_atoms)
{
    for (int p = blockIdx.x * 256 + threadIdx.x; p < n_pairs; p += gridDim.x * 256) {
        int ai = idx_i[p];
        if ((unsigned)ai < (unsigned)n_atoms) atomicAdd(&cnt[ai], 1);
    }
}

__global__ __launch_bounds__(1024) void scan1_kernel(
    const int* __restrict__ cnt, int* __restrict__ offs, int* __restrict__ partials, int n)
{
    __shared__ int sm[1024];
    int t = threadIdx.x, idx = blockIdx.x * 1024 + t;
    int v = (idx < n) ? cnt[idx] : 0;
    sm[t] = v;
    __syncthreads();
    #pragma unroll
    for (int d = 1; d < 1024; d <<= 1) {
        int tmp = (t >= d) ? sm[t - d] : 0;
        __syncthreads();
        sm[t] += tmp;
        __syncthreads();
    }
    if (idx < n) offs[idx] = sm[t] - v;
    if (t == 1023) partials[blockIdx.x] = sm[1023];
}

__global__ __launch_bounds__(64) void scan2_kernel(
    int* __restrict__ partials, int* __restrict__ offs, int nb, int n)
{
    __shared__ int sm[64];
    int t = threadIdx.x;
    int v = (t < nb) ? partials[t] : 0;
    sm[t] = v;
    __syncthreads();
    #pragma unroll
    for (int d = 1; d < 64; d <<= 1) {
        int tmp = (t >= d) ? sm[t - d] : 0;
        __syncthreads();
        sm[t] += tmp;
        __syncthreads();
    }
    if (t < nb) partials[t] = sm[t] - v;
    if (t == 63) offs[n] = sm[63];
}

__global__ __launch_bounds__(1024) void scan3_kernel(
    int* __restrict__ offs, int* __restrict__ cur, const int* __restrict__ partials, int n)
{
    int idx = blockIdx.x * 1024 + threadIdx.x;
    if (idx < n) {
        int o = offs[idx] + partials[blockIdx.x];
        offs[idx] = o;
        cur[idx] = o;
    }
}

// ---------- PAYLOAD PATH: physically sort pair payload ----------
// payload[pos] = { f_ij F16 x20 (40 B) | idx_j int (4 B) | rcut f32 (4 B) } = 48 B
// (f16, not bf16: feeds v_dot2_f32_f16 in the segment kernel with no unpacking;
// f16 also has 2 more mantissa bits than bf16 for f_ij in [0,1).)
// Block 0 additionally zeroes an 816 B slack region after the payload.
__global__ __launch_bounds__(256) void scatter_pay_kernel(
    const float* __restrict__ f_ij, const int* __restrict__ idx_i, const int* __restrict__ idx_j,
    const float* __restrict__ rcut, int* __restrict__ cur, uint4* __restrict__ pay,
    int n_pairs, int n_atoms)
{
    if (blockIdx.x == 0 && threadIdx.x < 204) {
        ((int*)(pay + (size_t)n_pairs * 3))[threadIdx.x] = 0;
    }
    for (int p = blockIdx.x * 256 + threadIdx.x; p < n_pairs; p += gridDim.x * 256) {
        int ai = idx_i[p];
        if ((unsigned)ai >= (unsigned)n_atoms) continue;
        int pos = atomicAdd(&cur[ai], 1);
        const float4* fr = (const float4*)(f_ij + (size_t)p * 20);
        float4 f0 = fr[0], f1 = fr[1], f2 = fr[2], f3 = fr[3], f4 = fr[4];
        uint4 q0, q1, q2;
        q0.x = pack2h(f0.x, f0.y); q0.y = pack2h(f0.z, f0.w);
        q0.z = pack2h(f1.x, f1.y); q0.w = pack2h(f1.z, f1.w);
        q1.x = pack2h(f2.x, f2.y); q1.y = pack2h(f2.z, f2.w);
        q1.z = pack2h(f3.x, f3.y); q1.w = pack2h(f3.z, f3.w);
        q2.x = pack2h(f4.x, f4.y); q2.y = pack2h(f4.z, f4.w);
        q2.z = (unsigned int)idx_j[p];
        q2.w = __float_as_uint(rcut[p]);
        uint4* dst = pay + (size_t)pos * 3;
        dst[0] = q0; dst[1] = q1; dst[2] = q2;
    }
}

// ---------- TIER-1: segment over sorted f16 payload, fdot2 + grid-stride waves ----------
// v3 (round 9). Round-8's global-atomic work queue serialized on one counter cell
// (40k device-scope atomics ping-ponging across 8 XCD L2s -> VALUBusy 13.6%,
// 559 µs). Same goal, ZERO atomics: static grid-stride assignment. 8192 waves,
// wave w handles atoms w, w+8192, ... (~5 atoms each). Amortizes the 40-load W_f
// setup over ~5 atoms, averages segment-length variance (block lifetime = max of
// 4 sums-of-5 instead of max of 4 singles: ~30% idle -> ~10%), keeps waves
// resident for gather-latency hiding. Inner loop byte-identical to the verified
// round-7 kernel (108 µs, absmax 0.0039).
__global__ __launch_bounds__(256) void segment_pay_f16_kernel(
    const uint4* __restrict__ pay, const float* __restrict__ W_f,
    const float* __restrict__ b_f, const unsigned int* __restrict__ hb32,
    const int* __restrict__ offs, float* __restrict__ agg, int n_atoms)
{
    const int lane = threadIdx.x & 63;
    const int wave_id = (blockIdx.x * 256 + threadIdx.x) >> 6;
    const int n_waves = gridDim.x * 4;

    const int c0 = 2 * lane;
    // packed W_f: w0p[r] = (W_f[c0][2r], W_f[c0][2r+1]) as f16 pair; w1p for c0+1
    h16x2 w0p[10], w1p[10];
    #pragma unroll
    for (int r = 0; r < 10; ++r) {
        h16x2 a, b;
        a[0] = (_Float16)W_f[c0 * 20 + 2 * r];
        a[1] = (_Float16)W_f[c0 * 20 + 2 * r + 1];
        b[0] = (_Float16)W_f[(c0 + 1) * 20 + 2 * r];
        b[1] = (_Float16)W_f[(c0 + 1) * 20 + 2 * r + 1];
        w0p[r] = a; w1p[r] = b;
    }
    const float b0 = b_f[c0], b1 = b_f[c0 + 1];

    for (int wave_atom = wave_id; wave_atom < n_atoms; wave_atom += n_waves) {
        const int cs = offs[wave_atom], ce = offs[wave_atom + 1];
        float acc0 = 0.f, acc1 = 0.f;

        int s = cs;
        for (; s + 2 <= ce; s += 2) {
            const uint4* pA = pay + (size_t)s * 3;
            const uint4* pB = pA + 3;
            uint4 qA0 = pA[0], qA1 = pA[1], qA2 = pA[2];
            uint4 qB0 = pB[0], qB1 = pB[1], qB2 = pB[2];
            unsigned int uA[10] = {qA0.x,qA0.y,qA0.z,qA0.w,qA1.x,qA1.y,qA1.z,qA1.w,qA2.x,qA2.y};
            unsigned int uB[10] = {qB0.x,qB0.y,qB0.z,qB0.w,qB1.x,qB1.y,qB1.z,qB1.w,qB2.x,qB2.y};
            float a0A = b0, a1A = b1, a0B = b0, a1B = b1;
            #pragma unroll
            for (int r = 0; r < 10; ++r) {
                h16x2 fA = u2h2(uA[r]);
                h16x2 fB = u2h2(uB[r]);
                a0A = fdot2(fA, w0p[r], a0A);
                a1A = fdot2(fA, w1p[r], a1A);
                a0B = fdot2(fB, w0p[r], a0B);
                a1B = fdot2(fB, w1p[r], a1B);
            }
            float rcA = __uint_as_float(qA2.w), rcB = __uint_as_float(qB2.w);
            float wv0A = ssp(a0A) * rcA, wv1A = ssp(a1A) * rcA;
            float wv0B = ssp(a0B) * rcB, wv1B = ssp(a1B) * rcB;
            unsigned int hA = hb32[(size_t)(int)qA2.z * 64 + lane];
            unsigned int hB = hb32[(size_t)(int)qB2.z * 64 + lane];
            acc0 += __uint_as_float(hA << 16) * wv0A + __uint_as_float(hB << 16) * wv0B;
            acc1 += __uint_as_float(hA & 0xffff0000u) * wv1A + __uint_as_float(hB & 0xffff0000u) * wv1B;
        }
        if (s < ce) {
            const uint4* pA = pay + (size_t)s * 3;
            uint4 q0 = pA[0], q1 = pA[1], q2 = pA[2];
            unsigned int u[10] = {q0.x,q0.y,q0.z,q0.w,q1.x,q1.y,q1.z,q1.w,q2.x,q2.y};
            float a0 = b0, a1 = b1;
            #pragma unroll
            for (int r = 0; r < 10; ++r) {
                h16x2 f = u2h2(u[r]);
                a0 = fdot2(f, w0p[r], a0);
                a1 = fdot2(f, w1p[r], a1);
            }
            float rc = __uint_as_float(q2.w);
            float wv0 = ssp(a0) * rc, wv1 = ssp(a1) * rc;
            unsigned int h = hb32[(size_t)(int)q2.z * 64 + lane];
            acc0 += __uint_as_float(h << 16) * wv0;
            acc1 += __uint_as_float(h & 0xffff0000u) * wv1;
        }

        *(float2*)&agg[(size_t)wave_atom * 128 + c0] = make_float2(acc0, acc1);
    }
}

// ---------- TIER-2 FALLBACK (proven): perm-indirected segment ----------
__global__ __launch_bounds__(256) void scatter_kernel(
    const int* __restrict__ idx_i, int* __restrict__ cur, int* __restrict__ perm,
    int n_pairs, int n_atoms)
{
    for (int p = blockIdx.x * 256 + threadIdx.x; p < n_pairs; p += gridDim.x * 256) {
        int ai = idx_i[p];
        if ((unsigned)ai < (unsigned)n_atoms) {
            int pos = atomicAdd(&cur[ai], 1);
            perm[pos] = p;
        }
    }
}

__global__ __launch_bounds__(256) void segment_kernel(
    const float* __restrict__ f_ij, const int* __restrict__ idx_j,
    const float* __restrict__ rcut, const float* __restrict__ W_f,
    const float* __restrict__ b_f, const unsigned short* __restrict__ hb,
    const int* __restrict__ offs, const int* __restrict__ perm,
    float* __restrict__ agg, int n_atoms)
{
    const int wave = (blockIdx.x * 256 + threadIdx.x) >> 6;
    const int lane = threadIdx.x & 63;
    if (wave >= n_atoms) return;

    float w0[20], w1[20];
    #pragma unroll
    for (int r = 0; r < 20; ++r) {
        w0[r] = W_f[lane * 20 + r];
        w1[r] = W_f[(lane + 64) * 20 + r];
    }
    const float b0 = b_f[lane], b1 = b_f[lane + 64];

    const int cs = offs[wave], ce = offs[wave + 1];
    float acc0 = 0.f, acc1 = 0.f;

    int s = cs;
    for (; s + 2 <= ce; s += 2) {
        int pA = perm[s], pB = perm[s + 1];
        int ajA = idx_j[pA], ajB = idx_j[pB];
        float rcA = rcut[pA], rcB = rcut[pB];
        const float4* frA = (const float4*)(f_ij + (size_t)pA * 20);
        const float4* frB = (const float4*)(f_ij + (size_t)pB * 20);
        float a0A = b0, a1A = b1, a0B = b0, a1B = b1;
        #pragma unroll
        for (int q = 0; q < 5; ++q) {
            float4 fA = frA[q], fB = frB[q];
            a0A += fA.x * w0[4*q+0]; a1A += fA.x * w1[4*q+0];
            a0A += fA.y * w0[4*q+1]; a1A += fA.y * w1[4*q+1];
            a0A += fA.z * w0[4*q+2]; a1A += fA.z * w1[4*q+2];
            a0A += fA.w * w0[4*q+3]; a1A += fA.w * w1[4*q+3];
            a0B += fB.x * w0[4*q+0]; a1B += fB.x * w1[4*q+0];
            a0B += fB.y * w0[4*q+1]; a1B += fB.y * w1[4*q+1];
            a0B += fB.z * w0[4*q+2]; a1B += fB.z * w1[4*q+2];
            a0B += fB.w * w0[4*q+3]; a1B += fB.w * w1[4*q+3];
        }
        float wv0A = ssp(a0A) * rcA, wv1A = ssp(a1A) * rcA;
        float wv0B = ssp(a0B) * rcB, wv1B = ssp(a1B) * rcB;
        float h0A = braw2f(hb[(size_t)ajA * 128 + lane]);
        float h1A = braw2f(hb[(size_t)ajA * 128 + 64 + lane]);
        float h0B = braw2f(hb[(size_t)ajB * 128 + lane]);
        float h1B = braw2f(hb[(size_t)ajB * 128 + 64 + lane]);
        acc0 += h0A * wv0A + h0B * wv0B;
        acc1 += h1A * wv1A + h1B * wv1B;
    }
    if (s < ce) {
        int p = perm[s];
        int aj = idx_j[p];
        float rc = rcut[p];
        const float4* fr = (const float4*)(f_ij + (size_t)p * 20);
        float a0 = b0, a1 = b1;
        #pragma unroll
        for (int q = 0; q < 5; ++q) {
            float4 fv = fr[q];
            a0 += fv.x * w0[4*q+0]; a1 += fv.x * w1[4*q+0];
            a0 += fv.y * w0[4*q+1]; a1 += fv.y * w1[4*q+1];
            a0 += fv.z * w0[4*q+2]; a1 += fv.z * w1[4*q+2];
            a0 += fv.w * w0[4*q+3]; a1 += fv.w * w1[4*q+3];
        }
        float wv0 = ssp(a0) * rc, wv1 = ssp(a1) * rc;
        acc0 += braw2f(hb[(size_t)aj * 128 + lane]) * wv0;
        acc1 += braw2f(hb[(size_t)aj * 128 + 64 + lane]) * wv1;
    }

    agg[(size_t)wave * 128 + lane]      = acc0;
    agg[(size_t)wave * 128 + 64 + lane] = acc1;
}

static inline size_t align_up(size_t v, size_t a) { return (v + a - 1) & ~(a - 1); }

extern "C" void kernel_launch(void* const* d_in, const int* in_sizes, int n_in,
                              void* d_out, int out_size, void* d_ws, size_t ws_size,
                              hipStream_t stream) {
    const float* x     = (const float*)d_in[0];
    const float* f_ij  = (const float*)d_in[1];
    const int*   idx_i = (const int*)d_in[2];
    const int*   idx_j = (const int*)d_in[3];
    const float* rcut  = (const float*)d_in[4];
    const float* W_in  = (const float*)d_in[5];
    const float* b_in  = (const float*)d_in[6];
    const float* W_f   = (const float*)d_in[7];
    const float* b_f   = (const float*)d_in[8];
    const float* W_out = (const float*)d_in[9];
    const float* b_out = (const float*)d_in[10];

    const int n_atoms = in_sizes[0] / 128;   // 40000
    const int n_pairs = in_sizes[2];         // 640000
    const int nscan = (n_atoms + 1023) / 1024;
    const int mfma_grid = (n_atoms + 63) / 64;

    // Tier-1 ws layout (payload path)
    size_t off_hb   = 0;
    size_t off_offs = align_up(off_hb + (size_t)n_atoms * 128 * 2, 16);
    size_t off_cur  = align_up(off_offs + (size_t)(n_atoms + 1) * 4, 16);
    size_t off_part = align_up(off_cur + (size_t)n_atoms * 4, 16);
    size_t off_pay  = align_up(off_part + (size_t)nscan * 4, 64);
    size_t need_pay = off_pay + (size_t)n_pairs * 48 + 816;

    if (ws_size >= need_pay) {
        // ---------- tier-1: f16 payload + fdot2 + grid-stride segment ----------
        unsigned short* hb = (unsigned short*)((char*)d_ws + off_hb);
        int*  offs = (int*)((char*)d_ws + off_offs);
        int*  cur  = (int*)((char*)d_ws + off_cur);
        int*  part = (int*)((char*)d_ws + off_part);
        uint4* pay = (uint4*)((char*)d_ws + off_pay);
        float* agg = (float*)d_out;

        linear128_mfma_kernel<false, true><<<dim3(mfma_grid), dim3(256), 0, stream>>>(
            x, W_in, b_in, (void*)hb, n_atoms);

        zero_int_kernel<<<dim3((n_atoms + 255) / 256), dim3(256), 0, stream>>>(cur, n_atoms);
        hist_kernel<<<dim3(1024), dim3(256), 0, stream>>>(idx_i, cur, n_pairs, n_atoms);
        scan1_kernel<<<dim3(nscan), dim3(1024), 0, stream>>>(cur, offs, part, n_atoms);
        scan2_kernel<<<dim3(1), dim3(64), 0, stream>>>(part, offs, nscan, n_atoms);
        scan3_kernel<<<dim3(nscan), dim3(1024), 0, stream>>>(offs, cur, part, n_atoms);
        scatter_pay_kernel<<<dim3(1024), dim3(256), 0, stream>>>(
            f_ij, idx_i, idx_j, rcut, cur, pay, n_pairs, n_atoms);

        segment_pay_f16_kernel<<<dim3(2048), dim3(256), 0, stream>>>(
            pay, W_f, b_f, (const unsigned int*)hb, offs, agg, n_atoms);

        linear128_mfma_kernel<true, false><<<dim3(mfma_grid), dim3(256), 0, stream>>>(
            agg, W_out, b_out, d_out, n_atoms);
    } else {
        // ---------- tier-2: exact round-8 pipeline (proven 419 µs) ----------
        size_t o_h    = 0;
        size_t o_offs = o_h + (size_t)n_atoms * 128 * 2;
        size_t o_cur  = o_offs + (size_t)(n_atoms + 1) * 4;
        size_t o_perm = o_cur + (size_t)n_atoms * 4;
        size_t o_part = o_perm + (size_t)n_pairs * 4;
        unsigned short* hb = (unsigned short*)((char*)d_ws + o_h);
        int* offs = (int*)((char*)d_ws + o_offs);
        int* cur  = (int*)((char*)d_ws + o_cur);
        int* perm = (int*)((char*)d_ws + o_perm);
        int* part = (int*)((char*)d_ws + o_part);
        float* agg = (float*)d_out;

        linear128_mfma_kernel<false, true><<<dim3(mfma_grid), dim3(256), 0, stream>>>(
            x, W_in, b_in, (void*)hb, n_atoms);

        zero_int_kernel<<<dim3((n_atoms + 255) / 256), dim3(256), 0, stream>>>(cur, n_atoms);
        hist_kernel<<<dim3(1024), dim3(256), 0, stream>>>(idx_i, cur, n_pairs, n_atoms);
        scan1_kernel<<<dim3(nscan), dim3(1024), 0, stream>>>(cur, offs, part, n_atoms);
        scan2_kernel<<<dim3(1), dim3(64), 0, stream>>>(part, offs, nscan, n_atoms);
        scan3_kernel<<<dim3(nscan), dim3(1024), 0, stream>>>(offs, cur, part, n_atoms);
        scatter_kernel<<<dim3(1024), dim3(256), 0, stream>>>(idx_i, cur, perm, n_pairs, n_atoms);

        segment_kernel<<<dim3((n_atoms + 3) / 4), dim3(256), 0, stream>>>(
            f_ij, idx_j, rcut, W_f, b_f, hb, offs, perm, agg, n_atoms);

        linear128_mfma_kernel<true, false><<<dim3(mfma_grid), dim3(256), 0, stream>>>(
            agg, W_out, b_out, d_out, n_atoms);
    }
}

// Round 10
// 316.880 us; speedup vs baseline: 2.4987x; 1.0669x over previous
//
#include <hip/hip_runtime.h>
#include <hip/hip_bf16.h>
#include <hip/hip_fp16.h>

typedef __hip_bfloat16 bf16;
typedef __attribute__((ext_vector_type(8))) short short8;   // 8 bf16 raw (4 VGPRs)
typedef __attribute__((ext_vector_type(4))) float f32x4;
typedef __attribute__((ext_vector_type(2))) _Float16 h16x2; // packed f16 pair

#if defined(__has_builtin)
#if __has_builtin(__builtin_amdgcn_fdot2)
#define HAVE_FDOT2 1
#endif
#endif

__device__ __forceinline__ float braw2f(unsigned short u) {
    return __uint_as_float(((unsigned int)u) << 16);
}
__device__ __forceinline__ unsigned short f2braw(float f) {
    bf16 b = __float2bfloat16(f);
    return *(unsigned short*)&b;
}
__device__ __forceinline__ unsigned int pack2(float lo, float hi) {
    return (unsigned int)f2braw(lo) | ((unsigned int)f2braw(hi) << 16);
}
// pack two floats as f16 pair (payload format for the fdot2 segment kernel)
__device__ __forceinline__ unsigned int pack2h(float lo, float hi) {
    __half l = __float2half(lo), h = __float2half(hi);
    return (unsigned int)*(unsigned short*)&l | ((unsigned int)*(unsigned short*)&h << 16);
}
// v_dot2_f32_f16: c += a.x*b.x + a.y*b.y in ONE VALU op (f32 accumulate)
__device__ __forceinline__ float fdot2(h16x2 a, h16x2 b, float c) {
#ifdef HAVE_FDOT2
    return __builtin_amdgcn_fdot2(a, b, c, false);
#else
    return c + (float)a[0] * (float)b[0] + (float)a[1] * (float)b[1];
#endif
}
__device__ __forceinline__ h16x2 u2h2(unsigned int u) {
    union { unsigned int u; h16x2 h; } cv; cv.u = u; return cv.h;
}

#define LN2F 0.69314718055994531f
// shifted softplus via native HW transcendentals (v_exp/v_log). Stable: arg<=0.
__device__ __forceinline__ float ssp(float x) {
    return fmaxf(x, 0.0f) + __logf(1.0f + __expf(-fabsf(x))) - LN2F;
}

// MFMA linear (round-8, verified): Y = (ACT? ssp:id)(X @ W^T + B), K=N=128.
// Block = 64 rows; in-place safe (block-private rows + barrier).
template<bool ACT, bool OUT_BF16>
__global__ __launch_bounds__(256) void linear128_mfma_kernel(
    const float* __restrict__ X, const float* __restrict__ W, const float* __restrict__ Bias,
    void* __restrict__ Yv, int n_rows)
{
    __shared__ unsigned short wls[128 * 128];
    __shared__ unsigned short xs[64 * 128];
    __shared__ float bls[128];

    const float4* W4 = (const float4*)W;
    for (int i = threadIdx.x; i < 128 * 32; i += 256) {
        float4 w = W4[i];
        ushort4 s; s.x = f2braw(w.x); s.y = f2braw(w.y); s.z = f2braw(w.z); s.w = f2braw(w.w);
        *(ushort4*)&wls[i * 4] = s;
    }
    if (threadIdx.x < 128) bls[threadIdx.x] = Bias[threadIdx.x];

    const int base = blockIdx.x * 64;
    const float4* X4 = (const float4*)X;
    for (int i = threadIdx.x; i < 64 * 32; i += 256) {
        int r = i >> 5, k4 = i & 31;
        int row = base + r;
        float4 v = (row < n_rows) ? X4[(size_t)row * 32 + k4] : make_float4(0.f, 0.f, 0.f, 0.f);
        ushort4 s; s.x = f2braw(v.x); s.y = f2braw(v.y); s.z = f2braw(v.z); s.w = f2braw(v.w);
        *(ushort4*)&xs[r * 128 + k4 * 4] = s;
    }
    __syncthreads();

    const int wv = threadIdx.x >> 6;
    const int l  = threadIdx.x & 63;
    const int lm = l & 15;
    const int lq = l >> 4;

    short8 a[4];
    #pragma unroll
    for (int kk = 0; kk < 4; ++kk)
        a[kk] = *(const short8*)&xs[(wv * 16 + lm) * 128 + kk * 32 + lq * 8];

    f32x4 acc[8];
    #pragma unroll
    for (int ct = 0; ct < 8; ++ct) {
        f32x4 c = {0.f, 0.f, 0.f, 0.f};
        #pragma unroll
        for (int kk = 0; kk < 4; ++kk) {
            short8 b = *(const short8*)&wls[(ct * 16 + lm) * 128 + kk * 32 + lq * 8];
            c = __builtin_amdgcn_mfma_f32_16x16x32_bf16(a[kk], b, c, 0, 0, 0);
        }
        acc[ct] = c;
    }

    #pragma unroll
    for (int ct = 0; ct < 8; ++ct) {
        int col = ct * 16 + lm;
        float bia = bls[col];
        #pragma unroll
        for (int r = 0; r < 4; ++r) {
            int row = base + wv * 16 + lq * 4 + r;
            if (row < n_rows) {
                float o = acc[ct][r] + bia;
                if (ACT) o = ssp(o);
                if (OUT_BF16) ((unsigned short*)Yv)[(size_t)row * 128 + col] = f2braw(o);
                else          ((float*)Yv)[(size_t)row * 128 + col] = o;
            }
        }
    }
}

// ---- counting sort by idx_i ----

__global__ __launch_bounds__(256) void zero_int_kernel(int* __restrict__ p, int n) {
    int i = blockIdx.x * 256 + threadIdx.x;
    if (i < n) p[i] = 0;
}

__global__ __launch_bounds__(256) void hist_kernel(
    const int* __restrict__ idx_i, int* __restrict__ cnt, int n_pairs, int n_atoms)
{
    for (int p = blockIdx.x * 256 + threadIdx.x; p < n_pairs; p += gridDim.x * 256) {
        int ai = idx_i[p];
        if ((unsigned)ai < (unsigned)n_atoms) atomicAdd(&cnt[ai], 1);
    }
}

__global__ __launch_bounds__(1024) void scan1_kernel(
    const int* __restrict__ cnt, int* __restrict__ offs, int* __restrict__ partials, int n)
{
    __shared__ int sm[1024];
    int t = threadIdx.x, idx = blockIdx.x * 1024 + t;
    int v = (idx < n) ? cnt[idx] : 0;
    sm[t] = v;
    __syncthreads();
    #pragma unroll
    for (int d = 1; d < 1024; d <<= 1) {
        int tmp = (t >= d) ? sm[t - d] : 0;
        __syncthreads();
        sm[t] += tmp;
        __syncthreads();
    }
    if (idx < n) offs[idx] = sm[t] - v;
    if (t == 1023) partials[blockIdx.x] = sm[1023];
}

__global__ __launch_bounds__(64) void scan2_kernel(
    int* __restrict__ partials, int* __restrict__ offs, int nb, int n)
{
    __shared__ int sm[64];
    int t = threadIdx.x;
    int v = (t < nb) ? partials[t] : 0;
    sm[t] = v;
    __syncthreads();
    #pragma unroll
    for (int d = 1; d < 64; d <<= 1) {
        int tmp = (t >= d) ? sm[t - d] : 0;
        __syncthreads();
        sm[t] += tmp;
        __syncthreads();
    }
    if (t < nb) partials[t] = sm[t] - v;
    if (t == 63) offs[n] = sm[63];
}

__global__ __launch_bounds__(1024) void scan3_kernel(
    int* __restrict__ offs, int* __restrict__ cur, const int* __restrict__ partials, int n)
{
    int idx = blockIdx.x * 1024 + threadIdx.x;
    if (idx < n) {
        int o = offs[idx] + partials[blockIdx.x];
        offs[idx] = o;
        cur[idx] = o;
    }
}

// ---------- PAYLOAD PATH: physically sort pair payload ----------
// payload[pos] = { f_ij F16 x20 (40 B) | idx_j int (4 B) | rcut f32 (4 B) } = 48 B
// (f16, not bf16: feeds v_dot2_f32_f16 in the segment kernel with no unpacking;
// f16 also has 2 more mantissa bits than bf16 for f_ij in [0,1).)
// Block 0 additionally zeroes an 816 B slack region after the payload.
__global__ __launch_bounds__(256) void scatter_pay_kernel(
    const float* __restrict__ f_ij, const int* __restrict__ idx_i, const int* __restrict__ idx_j,
    const float* __restrict__ rcut, int* __restrict__ cur, uint4* __restrict__ pay,
    int n_pairs, int n_atoms)
{
    if (blockIdx.x == 0 && threadIdx.x < 204) {
        ((int*)(pay + (size_t)n_pairs * 3))[threadIdx.x] = 0;
    }
    for (int p = blockIdx.x * 256 + threadIdx.x; p < n_pairs; p += gridDim.x * 256) {
        int ai = idx_i[p];
        if ((unsigned)ai >= (unsigned)n_atoms) continue;
        int pos = atomicAdd(&cur[ai], 1);
        const float4* fr = (const float4*)(f_ij + (size_t)p * 20);
        float4 f0 = fr[0], f1 = fr[1], f2 = fr[2], f3 = fr[3], f4 = fr[4];
        uint4 q0, q1, q2;
        q0.x = pack2h(f0.x, f0.y); q0.y = pack2h(f0.z, f0.w);
        q0.z = pack2h(f1.x, f1.y); q0.w = pack2h(f1.z, f1.w);
        q1.x = pack2h(f2.x, f2.y); q1.y = pack2h(f2.z, f2.w);
        q1.z = pack2h(f3.x, f3.y); q1.w = pack2h(f3.z, f3.w);
        q2.x = pack2h(f4.x, f4.y); q2.y = pack2h(f4.z, f4.w);
        q2.z = (unsigned int)idx_j[p];
        q2.w = __float_as_uint(rcut[p]);
        uint4* dst = pay + (size_t)pos * 3;
        dst[0] = q0; dst[1] = q1; dst[2] = q2;
    }
}

// ---------- TIER-1: segment over sorted f16 payload, fdot2 + scalarized loads ----------
// v4 (round 10). Config reverted to the verified round-7 launch (wave-per-atom,
// oversubscribed grid: the dispatcher BACKFILLS finished blocks, which beat both
// the atomic queue (r8, 559 µs: one counter cell serialized 8 XCDs) and static
// grid-stride (r9, 113 µs: no backfill -> dead slots)).
// New in v4: cs/ce made explicitly wave-uniform via readfirstlane. The whole
// loop-index/address chain for the payload records then becomes SGPR arithmetic,
// and LLVM's uniform-load scalarization can emit s_load_dwordx4 for the three
// wave-uniform record loads (const __restrict__, unclobbered): payload traffic
// moves to the scalar/SMEM pipe, leaving the vector memory pipe to the h-gather
// alone. fdot2 legally takes the SGPR payload word as its single SGPR operand.
// Also: W_f per-lane setup via 10 float4 loads (160 contiguous B/lane) instead
// of 40 scalar loads. Math identical to round-7 (108 µs, absmax 0.0039).
__global__ __launch_bounds__(256) void segment_pay_f16_kernel(
    const uint4* __restrict__ pay, const float* __restrict__ W_f,
    const float* __restrict__ b_f, const unsigned int* __restrict__ hb32,
    const int* __restrict__ offs, float* __restrict__ agg, int n_atoms)
{
    const int wave = (blockIdx.x * 256 + threadIdx.x) >> 6;
    const int lane = threadIdx.x & 63;
    if (wave >= n_atoms) return;

    const int c0 = 2 * lane;
    // rows c0 and c0+1 of W_f are 40 contiguous floats starting at W_f + c0*20
    // (16 B aligned: c0*20*4 = 160*lane). Load as 10 float4, then pack to f16 pairs.
    float wt[40];
    {
        const float4* wf4 = (const float4*)(W_f + (size_t)c0 * 20);
        #pragma unroll
        for (int r = 0; r < 10; ++r) {
            float4 v = wf4[r];
            wt[4 * r + 0] = v.x; wt[4 * r + 1] = v.y;
            wt[4 * r + 2] = v.z; wt[4 * r + 3] = v.w;
        }
    }
    h16x2 w0p[10], w1p[10];
    #pragma unroll
    for (int r = 0; r < 10; ++r) {
        h16x2 a, b;
        a[0] = (_Float16)wt[2 * r];
        a[1] = (_Float16)wt[2 * r + 1];
        b[0] = (_Float16)wt[20 + 2 * r];
        b[1] = (_Float16)wt[20 + 2 * r + 1];
        w0p[r] = a; w1p[r] = b;
    }
    const float b0 = b_f[c0], b1 = b_f[c0 + 1];

    // explicit wave-uniformity: scalarize the segment bounds (and thus all
    // payload record addresses derived from them)
    const int cs = __builtin_amdgcn_readfirstlane(offs[wave]);
    const int ce = __builtin_amdgcn_readfirstlane(offs[wave + 1]);
    float acc0 = 0.f, acc1 = 0.f;

    int s = cs;
    for (; s + 2 <= ce; s += 2) {
        const uint4* pA = pay + (size_t)s * 3;
        const uint4* pB = pA + 3;
        uint4 qA0 = pA[0], qA1 = pA[1], qA2 = pA[2];
        uint4 qB0 = pB[0], qB1 = pB[1], qB2 = pB[2];
        unsigned int uA[10] = {qA0.x,qA0.y,qA0.z,qA0.w,qA1.x,qA1.y,qA1.z,qA1.w,qA2.x,qA2.y};
        unsigned int uB[10] = {qB0.x,qB0.y,qB0.z,qB0.w,qB1.x,qB1.y,qB1.z,qB1.w,qB2.x,qB2.y};
        float a0A = b0, a1A = b1, a0B = b0, a1B = b1;
        #pragma unroll
        for (int r = 0; r < 10; ++r) {
            h16x2 fA = u2h2(uA[r]);
            h16x2 fB = u2h2(uB[r]);
            a0A = fdot2(fA, w0p[r], a0A);
            a1A = fdot2(fA, w1p[r], a1A);
            a0B = fdot2(fB, w0p[r], a0B);
            a1B = fdot2(fB, w1p[r], a1B);
        }
        float rcA = __uint_as_float(qA2.w), rcB = __uint_as_float(qB2.w);
        float wv0A = ssp(a0A) * rcA, wv1A = ssp(a1A) * rcA;
        float wv0B = ssp(a0B) * rcB, wv1B = ssp(a1B) * rcB;
        unsigned int hA = hb32[(size_t)(int)qA2.z * 64 + lane];
        unsigned int hB = hb32[(size_t)(int)qB2.z * 64 + lane];
        acc0 += __uint_as_float(hA << 16) * wv0A + __uint_as_float(hB << 16) * wv0B;
        acc1 += __uint_as_float(hA & 0xffff0000u) * wv1A + __uint_as_float(hB & 0xffff0000u) * wv1B;
    }
    if (s < ce) {
        const uint4* pA = pay + (size_t)s * 3;
        uint4 q0 = pA[0], q1 = pA[1], q2 = pA[2];
        unsigned int u[10] = {q0.x,q0.y,q0.z,q0.w,q1.x,q1.y,q1.z,q1.w,q2.x,q2.y};
        float a0 = b0, a1 = b1;
        #pragma unroll
        for (int r = 0; r < 10; ++r) {
            h16x2 f = u2h2(u[r]);
            a0 = fdot2(f, w0p[r], a0);
            a1 = fdot2(f, w1p[r], a1);
        }
        float rc = __uint_as_float(q2.w);
        float wv0 = ssp(a0) * rc, wv1 = ssp(a1) * rc;
        unsigned int h = hb32[(size_t)(int)q2.z * 64 + lane];
        acc0 += __uint_as_float(h << 16) * wv0;
        acc1 += __uint_as_float(h & 0xffff0000u) * wv1;
    }

    *(float2*)&agg[(size_t)wave * 128 + c0] = make_float2(acc0, acc1);
}

// ---------- TIER-2 FALLBACK (proven): perm-indirected segment ----------
__global__ __launch_bounds__(256) void scatter_kernel(
    const int* __restrict__ idx_i, int* __restrict__ cur, int* __restrict__ perm,
    int n_pairs, int n_atoms)
{
    for (int p = blockIdx.x * 256 + threadIdx.x; p < n_pairs; p += gridDim.x * 256) {
        int ai = idx_i[p];
        if ((unsigned)ai < (unsigned)n_atoms) {
            int pos = atomicAdd(&cur[ai], 1);
            perm[pos] = p;
        }
    }
}

__global__ __launch_bounds__(256) void segment_kernel(
    const float* __restrict__ f_ij, const int* __restrict__ idx_j,
    const float* __restrict__ rcut, const float* __restrict__ W_f,
    const float* __restrict__ b_f, const unsigned short* __restrict__ hb,
    const int* __restrict__ offs, const int* __restrict__ perm,
    float* __restrict__ agg, int n_atoms)
{
    const int wave = (blockIdx.x * 256 + threadIdx.x) >> 6;
    const int lane = threadIdx.x & 63;
    if (wave >= n_atoms) return;

    float w0[20], w1[20];
    #pragma unroll
    for (int r = 0; r < 20; ++r) {
        w0[r] = W_f[lane * 20 + r];
        w1[r] = W_f[(lane + 64) * 20 + r];
    }
    const float b0 = b_f[lane], b1 = b_f[lane + 64];

    const int cs = offs[wave], ce = offs[wave + 1];
    float acc0 = 0.f, acc1 = 0.f;

    int s = cs;
    for (; s + 2 <= ce; s += 2) {
        int pA = perm[s], pB = perm[s + 1];
        int ajA = idx_j[pA], ajB = idx_j[pB];
        float rcA = rcut[pA], rcB = rcut[pB];
        const float4* frA = (const float4*)(f_ij + (size_t)pA * 20);
        const float4* frB = (const float4*)(f_ij + (size_t)pB * 20);
        float a0A = b0, a1A = b1, a0B = b0, a1B = b1;
        #pragma unroll
        for (int q = 0; q < 5; ++q) {
            float4 fA = frA[q], fB = frB[q];
            a0A += fA.x * w0[4*q+0]; a1A += fA.x * w1[4*q+0];
            a0A += fA.y * w0[4*q+1]; a1A += fA.y * w1[4*q+1];
            a0A += fA.z * w0[4*q+2]; a1A += fA.z * w1[4*q+2];
            a0A += fA.w * w0[4*q+3]; a1A += fA.w * w1[4*q+3];
            a0B += fB.x * w0[4*q+0]; a1B += fB.x * w1[4*q+0];
            a0B += fB.y * w0[4*q+1]; a1B += fB.y * w1[4*q+1];
            a0B += fB.z * w0[4*q+2]; a1B += fB.z * w1[4*q+2];
            a0B += fB.w * w0[4*q+3]; a1B += fB.w * w1[4*q+3];
        }
        float wv0A = ssp(a0A) * rcA, wv1A = ssp(a1A) * rcA;
        float wv0B = ssp(a0B) * rcB, wv1B = ssp(a1B) * rcB;
        float h0A = braw2f(hb[(size_t)ajA * 128 + lane]);
        float h1A = braw2f(hb[(size_t)ajA * 128 + 64 + lane]);
        float h0B = braw2f(hb[(size_t)ajB * 128 + lane]);
        float h1B = braw2f(hb[(size_t)ajB * 128 + 64 + lane]);
        acc0 += h0A * wv0A + h0B * wv0B;
        acc1 += h1A * wv1A + h1B * wv1B;
    }
    if (s < ce) {
        int p = perm[s];
        int aj = idx_j[p];
        float rc = rcut[p];
        const float4* fr = (const float4*)(f_ij + (size_t)p * 20);
        float a0 = b0, a1 = b1;
        #pragma unroll
        for (int q = 0; q < 5; ++q) {
            float4 fv = fr[q];
            a0 += fv.x * w0[4*q+0]; a1 += fv.x * w1[4*q+0];
            a0 += fv.y * w0[4*q+1]; a1 += fv.y * w1[4*q+1];
            a0 += fv.z * w0[4*q+2]; a1 += fv.z * w1[4*q+2];
            a0 += fv.w * w0[4*q+3]; a1 += fv.w * w1[4*q+3];
        }
        float wv0 = ssp(a0) * rc, wv1 = ssp(a1) * rc;
        acc0 += braw2f(hb[(size_t)aj * 128 + lane]) * wv0;
        acc1 += braw2f(hb[(size_t)aj * 128 + 64 + lane]) * wv1;
    }

    agg[(size_t)wave * 128 + lane]      = acc0;
    agg[(size_t)wave * 128 + 64 + lane] = acc1;
}

static inline size_t align_up(size_t v, size_t a) { return (v + a - 1) & ~(a - 1); }

extern "C" void kernel_launch(void* const* d_in, const int* in_sizes, int n_in,
                              void* d_out, int out_size, void* d_ws, size_t ws_size,
                              hipStream_t stream) {
    const float* x     = (const float*)d_in[0];
    const float* f_ij  = (const float*)d_in[1];
    const int*   idx_i = (const int*)d_in[2];
    const int*   idx_j = (const int*)d_in[3];
    const float* rcut  = (const float*)d_in[4];
    const float* W_in  = (const float*)d_in[5];
    const float* b_in  = (const float*)d_in[6];
    const float* W_f   = (const float*)d_in[7];
    const float* b_f   = (const float*)d_in[8];
    const float* W_out = (const float*)d_in[9];
    const float* b_out = (const float*)d_in[10];

    const int n_atoms = in_sizes[0] / 128;   // 40000
    const int n_pairs = in_sizes[2];         // 640000
    const int nscan = (n_atoms + 1023) / 1024;
    const int mfma_grid = (n_atoms + 63) / 64;

    // Tier-1 ws layout (payload path)
    size_t off_hb   = 0;
    size_t off_offs = align_up(off_hb + (size_t)n_atoms * 128 * 2, 16);
    size_t off_cur  = align_up(off_offs + (size_t)(n_atoms + 1) * 4, 16);
    size_t off_part = align_up(off_cur + (size_t)n_atoms * 4, 16);
    size_t off_pay  = align_up(off_part + (size_t)nscan * 4, 64);
    size_t need_pay = off_pay + (size_t)n_pairs * 48 + 816;

    if (ws_size >= need_pay) {
        // ---------- tier-1: f16 payload + fdot2 + scalarized segment ----------
        unsigned short* hb = (unsigned short*)((char*)d_ws + off_hb);
        int*  offs = (int*)((char*)d_ws + off_offs);
        int*  cur  = (int*)((char*)d_ws + off_cur);
        int*  part = (int*)((char*)d_ws + off_part);
        uint4* pay = (uint4*)((char*)d_ws + off_pay);
        float* agg = (float*)d_out;

        linear128_mfma_kernel<false, true><<<dim3(mfma_grid), dim3(256), 0, stream>>>(
            x, W_in, b_in, (void*)hb, n_atoms);

        zero_int_kernel<<<dim3((n_atoms + 255) / 256), dim3(256), 0, stream>>>(cur, n_atoms);
        hist_kernel<<<dim3(1024), dim3(256), 0, stream>>>(idx_i, cur, n_pairs, n_atoms);
        scan1_kernel<<<dim3(nscan), dim3(1024), 0, stream>>>(cur, offs, part, n_atoms);
        scan2_kernel<<<dim3(1), dim3(64), 0, stream>>>(part, offs, nscan, n_atoms);
        scan3_kernel<<<dim3(nscan), dim3(1024), 0, stream>>>(offs, cur, part, n_atoms);
        scatter_pay_kernel<<<dim3(1024), dim3(256), 0, stream>>>(
            f_ij, idx_i, idx_j, rcut, cur, pay, n_pairs, n_atoms);

        segment_pay_f16_kernel<<<dim3((n_atoms + 3) / 4), dim3(256), 0, stream>>>(
            pay, W_f, b_f, (const unsigned int*)hb, offs, agg, n_atoms);

        linear128_mfma_kernel<true, false><<<dim3(mfma_grid), dim3(256), 0, stream>>>(
            agg, W_out, b_out, d_out, n_atoms);
    } else {
        // ---------- tier-2: exact round-8 pipeline (proven 419 µs) ----------
        size_t o_h    = 0;
        size_t o_offs = o_h + (size_t)n_atoms * 128 * 2;
        size_t o_cur  = o_offs + (size_t)(n_atoms + 1) * 4;
        size_t o_perm = o_cur + (size_t)n_atoms * 4;
        size_t o_part = o_perm + (size_t)n_pairs * 4;
        unsigned short* hb = (unsigned short*)((char*)d_ws + o_h);
        int* offs = (int*)((char*)d_ws + o_offs);
        int* cur  = (int*)((char*)d_ws + o_cur);
        int* perm = (int*)((char*)d_ws + o_perm);
        int* part = (int*)((char*)d_ws + o_part);
        float* agg = (float*)d_out;

        linear128_mfma_kernel<false, true><<<dim3(mfma_grid), dim3(256), 0, stream>>>(
            x, W_in, b_in, (void*)hb, n_atoms);

        zero_int_kernel<<<dim3((n_atoms + 255) / 256), dim3(256), 0, stream>>>(cur, n_atoms);
        hist_kernel<<<dim3(1024), dim3(256), 0, stream>>>(idx_i, cur, n_pairs, n_atoms);
        scan1_kernel<<<dim3(nscan), dim3(1024), 0, stream>>>(cur, offs, part, n_atoms);
        scan2_kernel<<<dim3(1), dim3(64), 0, stream>>>(part, offs, nscan, n_atoms);
        scan3_kernel<<<dim3(nscan), dim3(1024), 0, stream>>>(offs, cur, part, n_atoms);
        scatter_kernel<<<dim3(1024), dim3(256), 0, stream>>>(idx_i, cur, perm, n_pairs, n_atoms);

        segment_kernel<<<dim3((n_atoms + 3) / 4), dim3(256), 0, stream>>>(
            f_ij, idx_j, rcut, W_f, b_f, hb, offs, perm, agg, n_atoms);

        linear128_mfma_kernel<true, false><<<dim3(mfma_grid), dim3(256), 0, stream>>>(
            agg, W_out, b_out, d_out, n_atoms);
    }
}